// Round 5
// baseline (268.744 us; speedup 1.0000x reference)
//
#include <hip/hip_runtime.h>
#include <math.h>

// (B, F, NP, DIM, H, DH) = (4, 16, 196, 512, 8, 64)
#define B_   4
#define F_   16
#define NP_  196
#define DIM_ 512
#define H_   8
#define DH_  64
#define NTOT 3137            // 1 + F*NP
#define BH_  32              // B*H
#define MROWS 12548          // B*NTOT
#define QSZ_ ((size_t)BH_ * NTOT * DH_)   // elements per q/k/v buffer
#define KVPAD 224            // kv padded to 7 ksteps of 32
#define PSTRIDE 232          // P LDS row stride (u16): 16B-aligned, read-conflict-free
#define NCHUNK 13            // cls kv chunks of 256

typedef unsigned short u16;
typedef __attribute__((ext_vector_type(8))) short    bf16x8;
typedef __attribute__((ext_vector_type(8))) unsigned short u16x8;
typedef __attribute__((ext_vector_type(4))) unsigned short u16x4;
typedef __attribute__((ext_vector_type(4))) float    f32x4;

__device__ __forceinline__ u16 f2bf(float f) {
    unsigned int u = __float_as_uint(f);
    unsigned int r = (u + 0x7FFFu + ((u >> 16) & 1u)) >> 16;
    return (u16)r;
}
__device__ __forceinline__ float bf2f(u16 u) {
    return __uint_as_float(((unsigned int)u) << 16);
}

// async global->LDS, 16B per lane. LDS dest must be wave-uniform base + lane*16.
__device__ __forceinline__ void gl2lds16(const u16* g, u16* l) {
    __builtin_amdgcn_global_load_lds(
        (const __attribute__((address_space(1))) unsigned int*)(g),
        (__attribute__((address_space(3))) unsigned int*)(l),
        16, 0, 0);
}

// ---------------------------------------------------------------------------
// convert x (fp32, MROWS x 512) -> bf16
// ---------------------------------------------------------------------------
__global__ __launch_bounds__(256) void convert_x_kernel(
    const float* __restrict__ x, u16* __restrict__ xbf)
{
    int idx = blockIdx.x * 256 + threadIdx.x;       // one float4 per thread
    float4 v = ((const float4*)x)[idx];
    u16x4 p = { f2bf(v.x), f2bf(v.y), f2bf(v.z), f2bf(v.w) };
    *(u16x4*)(&xbf[(size_t)idx * 4]) = p;
}

// ---------------------------------------------------------------------------
// transpose + bf16-convert: src (R x C fp32) -> dst (C x R bf16)
// ---------------------------------------------------------------------------
__global__ __launch_bounds__(256) void transpose_bf16_kernel(
    const float* __restrict__ src, u16* __restrict__ dst, int R, int C)
{
    __shared__ float t[32][33];
    const int tx = threadIdx.x & 31, ty = threadIdx.x >> 5;   // ty in 0..7
    const int c0 = blockIdx.x * 32, r0 = blockIdx.y * 32;
    #pragma unroll
    for (int i = 0; i < 4; ++i) {
        int r = ty + i * 8;
        t[r][tx] = src[(size_t)(r0 + r) * C + c0 + tx];
    }
    __syncthreads();
    #pragma unroll
    for (int i = 0; i < 4; ++i) {
        int cc = ty + i * 8;
        dst[(size_t)(c0 + cc) * R + r0 + tx] = f2bf(t[tx][cc]);
    }
}

// ---------------------------------------------------------------------------
// bf16 MFMA GEMM with prefetch-across-barrier software pipeline.
//   C = A(MROWS x 512) * BT^T   (BT is N x 512 bf16, K-contig)
// Block tile: (MI*32) x 128, BK=32, 4 waves 2x2; wave computes (MI*16) x 64.
// Double-buffered LDS; global_load_lds for k+1 issued right AFTER the
// barrier, so the next barrier's vmcnt(0) drain finds them already complete
// (the MFMA phase covers the latency). One barrier per K-iteration.
// MODE 0 (MI=8): qkv epilogue -> bf16 q (x0.125) / k / v [bh][n][64]
// MODE 1 (MI=4): out epilogue (+bias, fp32 row-major)
// ---------------------------------------------------------------------------
template<int MODE, int MI>
__global__ __launch_bounds__(256, 2) void gemm_bf16_mfma(
    const u16* __restrict__ A, const u16* __restrict__ BT,
    u16* __restrict__ Cq, u16* __restrict__ Ck, u16* __restrict__ Cv,
    float* __restrict__ Cout, const float* __restrict__ bias)
{
    constexpr int ASUB = MI * 2;               // A subtiles (16 rows each) per k-step
    __shared__ alignas(16) u16 Asm[2][ASUB * 512];
    __shared__ alignas(16) u16 Bsm[2][8 * 512];

    const int tid  = threadIdx.x;
    const int wave = tid >> 6, lane = tid & 63;
    const int wr = wave >> 1, wc = wave & 1;
    const int lm = lane & 15, lq = lane >> 4;
    const int row0 = blockIdx.y * (MI * 32);
    const int col0 = blockIdx.x * 128;

    f32x4 acc[MI][4];
    #pragma unroll
    for (int i = 0; i < MI; ++i)
        #pragma unroll
        for (int j = 0; j < 4; ++j) acc[i][j] = (f32x4){0.f, 0.f, 0.f, 0.f};

    auto stage = [&](int k0, int buf) {
        #pragma unroll
        for (int i = 0; i < ASUB / 4; ++i) {
            int s = wave * (ASUB / 4) + i;
            int arow = row0 + s * 16 + lm;
            if (arow >= MROWS) arow = MROWS - 1;
            gl2lds16(A + (size_t)arow * 512 + k0 + lq * 8, &Asm[buf][s * 512 + lane * 8]);
        }
        #pragma unroll
        for (int i = 0; i < 2; ++i) {
            int s = wave * 2 + i;
            int brow = col0 + s * 16 + lm;      // row of BT = output column
            gl2lds16(BT + (size_t)brow * 512 + k0 + lq * 8, &Bsm[buf][s * 512 + lane * 8]);
        }
    };

    stage(0, 0);                                // prologue prefetch
    for (int it = 0; it < 16; ++it) {
        __syncthreads();                        // drains buf[it&1] loads (in flight
                                                // for a whole MFMA phase) + wg sync
        if (it < 15) stage((it + 1) * 32, (it + 1) & 1);   // prefetch next tile
        const int buf = it & 1;
        bf16x8 af[MI], bf[4];
        #pragma unroll
        for (int mi = 0; mi < MI; ++mi)
            af[mi] = *(const bf16x8*)(&Asm[buf][(wr * MI + mi) * 512 + lane * 8]);
        #pragma unroll
        for (int ni = 0; ni < 4; ++ni)
            bf[ni] = *(const bf16x8*)(&Bsm[buf][(wc * 4 + ni) * 512 + lane * 8]);
        #pragma unroll
        for (int mi = 0; mi < MI; ++mi)
            #pragma unroll
            for (int ni = 0; ni < 4; ++ni)
                acc[mi][ni] = __builtin_amdgcn_mfma_f32_16x16x32_bf16(
                    af[mi], bf[ni], acc[mi][ni], 0, 0, 0);
    }

    // epilogue: lane l, reg r -> row = sub16 + lq*4 + r, col = sub16 + lm
    if (MODE == 0) {
        const int t3 = col0 >> 9;               // uniform per block: 0=q 1=k 2=v
        #pragma unroll
        for (int mi = 0; mi < MI; ++mi) {
            #pragma unroll
            for (int r = 0; r < 4; ++r) {
                int gr = row0 + wr * (MI * 16) + mi * 16 + lq * 4 + r;
                if (gr >= MROWS) continue;
                int b = gr / NTOT;
                int n = gr - b * NTOT;
                #pragma unroll
                for (int ni = 0; ni < 4; ++ni) {
                    int gc = col0 + wc * 64 + ni * 16 + lm;
                    int rem = gc & 511;
                    int h = rem >> 6, d = rem & 63;
                    size_t tok = (size_t)(b * H_ + h) * NTOT + n;
                    float v = acc[mi][ni][r];
                    if (t3 == 0)      Cq[tok * 64 + d] = f2bf(v * 0.125f);
                    else if (t3 == 1) Ck[tok * 64 + d] = f2bf(v);
                    else              Cv[tok * 64 + d] = f2bf(v);
                }
            }
        }
    } else {
        float bb[4];
        #pragma unroll
        for (int ni = 0; ni < 4; ++ni)
            bb[ni] = bias[col0 + wc * 64 + ni * 16 + lm];
        #pragma unroll
        for (int mi = 0; mi < MI; ++mi) {
            #pragma unroll
            for (int r = 0; r < 4; ++r) {
                int gr = row0 + wr * (MI * 16) + mi * 16 + lq * 4 + r;
                if (gr >= MROWS) continue;
                #pragma unroll
                for (int ni = 0; ni < 4; ++ni) {
                    int gc = col0 + wc * 64 + ni * 16 + lm;
                    Cout[(size_t)gr * 512 + gc] = acc[mi][ni][r] + bb[ni];
                }
            }
        }
    }
}

// ---------------------------------------------------------------------------
// build per-group V^T [bh*16+f][64][KVPAD] from vbuf (incl. cls row, zero pad)
// ---------------------------------------------------------------------------
__global__ __launch_bounds__(256) void vt_build_kernel(
    const u16* __restrict__ vb, u16* __restrict__ vT)
{
    const int g = blockIdx.x;                   // bh*16 + f
    const int bh = g >> 4, f = g & 15;
    const int d = threadIdx.x & 63, jq = threadIdx.x >> 6;
    const int j0 = blockIdx.y * 32;
    u16* dst = vT + ((size_t)g * 64 + d) * KVPAD;
    #pragma unroll
    for (int i = 0; i < 8; ++i) {
        int jj = j0 + i * 4 + jq;
        u16 val = 0;
        if (jj <= 196) {
            int n = (jj == 0) ? 0 : (1 + f * NP_ + jj - 1);
            val = vb[((size_t)bh * NTOT + n) * 64 + d];
        }
        dst[jj] = val;
    }
}

// ---------------------------------------------------------------------------
// local attention, MFMA flash. One wave = one (bh, f, 16-q-row tile).
// ---------------------------------------------------------------------------
__global__ __launch_bounds__(256) void attn_mfma_kernel(
    const u16* __restrict__ qb, const u16* __restrict__ kb,
    const u16* __restrict__ vT, u16* __restrict__ attn)
{
    __shared__ alignas(16) u16 Pbuf[4 * 16 * PSTRIDE];

    const int tid  = threadIdx.x;
    const int wave = tid >> 6, lane = tid & 63;
    const int lm = lane & 15, lq = lane >> 4;
    const int task = blockIdx.x * 4 + wave;          // 0..6655
    const int mt = task % 13;
    const int gf = task / 13;
    const int f  = gf & 15;
    const int bh = gf >> 4;

    const int rq = min(mt * 16 + lm, 195);
    const u16* qrow = qb + ((size_t)bh * NTOT + (1 + f * NP_ + rq)) * 64;
    bf16x8 qf0 = *(const bf16x8*)(qrow + lq * 8);
    bf16x8 qf1 = *(const bf16x8*)(qrow + 32 + lq * 8);

    // S = Q K^T over 13 kv tiles of 16 (kv j = nt*16 + lm; j==0 is cls)
    f32x4 S[13];
    #pragma unroll
    for (int nt = 0; nt < 13; ++nt) {
        int rkc = min(nt * 16 + lm, 196);
        int nk = (rkc == 0) ? 0 : (1 + f * NP_ + rkc - 1);
        const u16* krow = kb + ((size_t)bh * NTOT + nk) * 64;
        bf16x8 kf0 = *(const bf16x8*)(krow + lq * 8);
        bf16x8 kf1 = *(const bf16x8*)(krow + 32 + lq * 8);
        f32x4 z = (f32x4){0.f, 0.f, 0.f, 0.f};
        z = __builtin_amdgcn_mfma_f32_16x16x32_bf16(qf0, kf0, z, 0, 0, 0);
        z = __builtin_amdgcn_mfma_f32_16x16x32_bf16(qf1, kf1, z, 0, 0, 0);
        S[nt] = z;
    }

    #pragma unroll
    for (int nt = 0; nt < 13; ++nt)
        if (nt * 16 + lm >= 197) {
            S[nt][0] = -INFINITY; S[nt][1] = -INFINITY;
            S[nt][2] = -INFINITY; S[nt][3] = -INFINITY;
        }

    // single-pass softmax; row = lq*4 + r, cols across the 16-lane group
    float invl[4];
    #pragma unroll
    for (int r = 0; r < 4; ++r) {
        float mx = -INFINITY;
        #pragma unroll
        for (int nt = 0; nt < 13; ++nt) mx = fmaxf(mx, S[nt][r]);
        mx = fmaxf(mx, __shfl_xor(mx, 1, 64));
        mx = fmaxf(mx, __shfl_xor(mx, 2, 64));
        mx = fmaxf(mx, __shfl_xor(mx, 4, 64));
        mx = fmaxf(mx, __shfl_xor(mx, 8, 64));
        float sum = 0.f;
        #pragma unroll
        for (int nt = 0; nt < 13; ++nt) {
            float p = __expf(S[nt][r] - mx);   // exp(-inf)=0 for masked cols
            S[nt][r] = p;
            sum += p;
        }
        sum += __shfl_xor(sum, 1, 64);
        sum += __shfl_xor(sum, 2, 64);
        sum += __shfl_xor(sum, 4, 64);
        sum += __shfl_xor(sum, 8, 64);
        invl[r] = 1.f / sum;
    }

    // P -> LDS (C-layout scatter), then re-read as A-fragments
    u16* P = Pbuf + wave * 16 * PSTRIDE;
    #pragma unroll
    for (int nt = 0; nt < 13; ++nt) {
        int col = nt * 16 + lm;
        #pragma unroll
        for (int r = 0; r < 4; ++r)
            P[(lq * 4 + r) * PSTRIDE + col] = f2bf(S[nt][r]);
    }
    {   // zero cols 208..223 (A-frag reads cover up to col 224)
        u16x4 z4 = {0, 0, 0, 0};
        *(u16x4*)(P + lm * PSTRIDE + 208 + lq * 4) = z4;
    }

    // O = P * V  (B operand from per-group V^T, kv-contiguous)
    f32x4 O[4];
    #pragma unroll
    for (int nd = 0; nd < 4; ++nd) O[nd] = (f32x4){0.f, 0.f, 0.f, 0.f};
    const u16* vbase = vT + (size_t)(bh * 16 + f) * 64 * KVPAD;
    #pragma unroll
    for (int ks = 0; ks < 7; ++ks) {
        bf16x8 pf = *(const bf16x8*)(P + lm * PSTRIDE + ks * 32 + lq * 8);
        #pragma unroll
        for (int nd = 0; nd < 4; ++nd) {
            bf16x8 vf = *(const bf16x8*)(vbase + (size_t)(nd * 16 + lm) * KVPAD + ks * 32 + lq * 8);
            O[nd] = __builtin_amdgcn_mfma_f32_16x16x32_bf16(pf, vf, O[nd], 0, 0, 0);
        }
    }

    const int b = bh >> 3, h = bh & 7;
    #pragma unroll
    for (int r = 0; r < 4; ++r) {
        int rql = mt * 16 + lq * 4 + r;
        if (rql >= 196) continue;
        int n = 1 + f * NP_ + rql;
        u16* dst = attn + ((size_t)b * NTOT + n) * 512 + h * 64;
        float s = invl[r];
        #pragma unroll
        for (int nd = 0; nd < 4; ++nd)
            dst[nd * 16 + lm] = f2bf(O[nd][r] * s);
    }
}

// ---------------------------------------------------------------------------
// cls attention, stage 1: grid (13 chunks, 32 bh), 256 threads.
// Phase A: thread = kv row; Phase B: thread = (quarter, d).
// ---------------------------------------------------------------------------
__global__ __launch_bounds__(256) void attn_cls_partial_kernel(
    const u16* __restrict__ qb, const u16* __restrict__ kb,
    const u16* __restrict__ vb, float* __restrict__ cls_m,
    float* __restrict__ cls_l, float* __restrict__ cls_o)
{
    __shared__ float qs[64];
    __shared__ float redm[4], redl[4];
    __shared__ float ps[256];
    __shared__ float so[4][64];

    const int c = blockIdx.x, bh = blockIdx.y;
    const int t = threadIdx.x;
    const int lane = t & 63, w = t >> 6;

    if (t < 64) qs[t] = bf2f(qb[(size_t)bh * NTOT * 64 + t]);   // q row 0, pre-scaled
    __syncthreads();

    // phase A: score for kv row j = c*256 + t
    const int j = c * 256 + t;
    const bool valid = (j < NTOT);
    const int jc = valid ? j : (NTOT - 1);
    const u16* krow = kb + ((size_t)bh * NTOT + jc) * 64;
    float s0 = 0.f, s1 = 0.f, s2 = 0.f, s3 = 0.f;
    #pragma unroll
    for (int i = 0; i < 8; ++i) {
        u16x8 k8 = *(const u16x8*)(krow + i * 8);
        const float* qp = qs + i * 8;
        s0 = fmaf(qp[0], bf2f(k8[0]), s0);
        s1 = fmaf(qp[1], bf2f(k8[1]), s1);
        s2 = fmaf(qp[2], bf2f(k8[2]), s2);
        s3 = fmaf(qp[3], bf2f(k8[3]), s3);
        s0 = fmaf(qp[4], bf2f(k8[4]), s0);
        s1 = fmaf(qp[5], bf2f(k8[5]), s1);
        s2 = fmaf(qp[6], bf2f(k8[6]), s2);
        s3 = fmaf(qp[7], bf2f(k8[7]), s3);
    }
    float s = (s0 + s1) + (s2 + s3);
    if (!valid) s = -INFINITY;

    // block max
    float mx = s;
    #pragma unroll
    for (int off = 1; off < 64; off <<= 1) mx = fmaxf(mx, __shfl_xor(mx, off, 64));
    if (lane == 0) redm[w] = mx;
    __syncthreads();
    mx = fmaxf(fmaxf(redm[0], redm[1]), fmaxf(redm[2], redm[3]));

    float pv = __expf(s - mx);                 // -inf -> 0
    float l = pv;
    #pragma unroll
    for (int off = 1; off < 64; off <<= 1) l += __shfl_xor(l, off, 64);
    if (lane == 0) redl[w] = l;
    ps[t] = pv;
    __syncthreads();
    l = redl[0] + redl[1] + redl[2] + redl[3];

    // phase B: o_d partial over this chunk's quarter
    const int d = lane, part = w;
    float o = 0.f;
    #pragma unroll 8
    for (int i = 0; i < 64; ++i) {
        int jj = c * 256 + part * 64 + i;
        int jjc = (jj < NTOT) ? jj : (NTOT - 1);
        o = fmaf(ps[part * 64 + i], bf2f(vb[((size_t)bh * NTOT + jjc) * 64 + d]), o);
    }
    so[part][d] = o;
    __syncthreads();
    if (t < 64) {
        float O = so[0][t] + so[1][t] + so[2][t] + so[3][t];
        int pi = bh * NCHUNK + c;
        cls_o[(size_t)pi * 64 + t] = O;
        if (t == 0) { cls_m[pi] = mx; cls_l[pi] = l; }
    }
}

// cls stage 2: merge 13 partials per bh, write bf16 row n=0.
__global__ __launch_bounds__(64) void attn_cls_merge_kernel(
    const float* __restrict__ cls_m, const float* __restrict__ cls_l,
    const float* __restrict__ cls_o, u16* __restrict__ attn)
{
    const int bh = blockIdx.x, lane = threadIdx.x;
    float M = -INFINITY;
    #pragma unroll
    for (int p = 0; p < NCHUNK; ++p) M = fmaxf(M, cls_m[bh * NCHUNK + p]);
    float L = 0.f, O = 0.f;
    #pragma unroll
    for (int p = 0; p < NCHUNK; ++p) {
        float al = __expf(cls_m[bh * NCHUNK + p] - M);
        L += cls_l[bh * NCHUNK + p] * al;
        O += cls_o[(size_t)(bh * NCHUNK + p) * 64 + lane] * al;
    }
    const int b = bh >> 3, h = bh & 7;
    attn[(size_t)b * NTOT * 512 + h * 64 + lane] = f2bf(O / L);
}

// ---------------------------------------------------------------------------
extern "C" void kernel_launch(void* const* d_in, const int* in_sizes, int n_in,
                              void* d_out, int out_size, void* d_ws, size_t ws_size,
                              hipStream_t stream) {
    const float* x    = (const float*)d_in[0];
    const float* wqkv = (const float*)d_in[1];
    const float* wout = (const float*)d_in[2];
    const float* bout = (const float*)d_in[3];

    u16* p = (u16*)d_ws;
    u16* xbf   = p;                    p += (size_t)MROWS * 512;  // reused as attn
    u16* attn  = xbf;                  // safe: xbf consumed by qkv gemm before attn writes
    u16* wqkvT = p;                    p += (size_t)1536 * 512;
    u16* woutT = p;                    p += (size_t)512 * 512;
    u16* qbuf  = p;                    p += QSZ_;
    u16* kbuf  = p;                    p += QSZ_;
    u16* vbuf  = p;                    p += QSZ_;
    u16* vT    = p;                    p += (size_t)BH_ * 16 * 64 * KVPAD;
    float* clsws = (float*)p;
    float* cls_m = clsws;                       // [32*13]
    float* cls_l = clsws + BH_ * NCHUNK;        // [32*13]
    float* cls_o = clsws + 2 * BH_ * NCHUNK;    // [32*13][64]
    float* outp  = (float*)d_out;

    // input conversions
    convert_x_kernel<<<6274, 256, 0, stream>>>(x, xbf);
    transpose_bf16_kernel<<<dim3(48, 16), 256, 0, stream>>>(wqkv, wqkvT, 512, 1536);
    transpose_bf16_kernel<<<dim3(16, 16), 256, 0, stream>>>(wout, woutT, 512, 512);
    // qkv = x @ W_qkv (bf16 MFMA, 256x128 tile, pipelined) -> bf16 q/k/v
    gemm_bf16_mfma<0, 8><<<dim3(12, 50), 256, 0, stream>>>(
        xbf, wqkvT, qbuf, kbuf, vbuf, nullptr, nullptr);
    // per-group V^T (incl. cls row + zero pad)
    vt_build_kernel<<<dim3(512, 7), 256, 0, stream>>>(vbuf, vT);
    // attention
    attn_mfma_kernel<<<1664, 256, 0, stream>>>(qbuf, kbuf, vT, attn);
    attn_cls_partial_kernel<<<dim3(NCHUNK, 32), 256, 0, stream>>>(
        qbuf, kbuf, vbuf, cls_m, cls_l, cls_o);
    attn_cls_merge_kernel<<<32, 64, 0, stream>>>(cls_m, cls_l, cls_o, attn);
    // out = attn @ W_out + b_out (bf16 MFMA, 128x128 tile, pipelined)
    gemm_bf16_mfma<1, 4><<<dim3(4, 99), 256, 0, stream>>>(
        attn, woutT, nullptr, nullptr, nullptr, outp, bout);
}

// Round 6
// 258.366 us; speedup vs baseline: 1.0402x; 1.0402x over previous
//
#include <hip/hip_runtime.h>
#include <math.h>

// (B, F, NP, DIM, H, DH) = (4, 16, 196, 512, 8, 64)
#define B_   4
#define F_   16
#define NP_  196
#define DIM_ 512
#define H_   8
#define DH_  64
#define NTOT 3137            // 1 + F*NP
#define BH_  32              // B*H
#define MROWS 12548          // B*NTOT
#define QSZ_ ((size_t)BH_ * NTOT * DH_)   // elements per q/k/v buffer
#define KVPAD 224            // kv padded to 7 ksteps of 32
#define PSTRIDE 232          // P LDS row stride (u16): 16B-aligned, read-conflict-free
#define NCHUNK 13            // cls kv chunks of 256

typedef unsigned short u16;
typedef __attribute__((ext_vector_type(8))) short    bf16x8;
typedef __attribute__((ext_vector_type(8))) unsigned short u16x8;
typedef __attribute__((ext_vector_type(4))) unsigned short u16x4;
typedef __attribute__((ext_vector_type(4))) float    f32x4;

__device__ __forceinline__ u16 f2bf(float f) {
    unsigned int u = __float_as_uint(f);
    unsigned int r = (u + 0x7FFFu + ((u >> 16) & 1u)) >> 16;
    return (u16)r;
}
__device__ __forceinline__ float bf2f(u16 u) {
    return __uint_as_float(((unsigned int)u) << 16);
}

// async global->LDS, 16B per lane. LDS dest must be wave-uniform base + lane*16.
__device__ __forceinline__ void gl2lds16(const u16* g, u16* l) {
    __builtin_amdgcn_global_load_lds(
        (const __attribute__((address_space(1))) unsigned int*)(g),
        (__attribute__((address_space(3))) unsigned int*)(l),
        16, 0, 0);
}

// ---------------------------------------------------------------------------
// convert x (fp32, MROWS x 512) -> bf16
// ---------------------------------------------------------------------------
__global__ __launch_bounds__(256) void convert_x_kernel(
    const float* __restrict__ x, u16* __restrict__ xbf)
{
    int idx = blockIdx.x * 256 + threadIdx.x;       // one float4 per thread
    float4 v = ((const float4*)x)[idx];
    u16x4 p = { f2bf(v.x), f2bf(v.y), f2bf(v.z), f2bf(v.w) };
    *(u16x4*)(&xbf[(size_t)idx * 4]) = p;
}

// ---------------------------------------------------------------------------
// transpose + bf16-convert: src (R x C fp32) -> dst (C x R bf16)
// ---------------------------------------------------------------------------
__global__ __launch_bounds__(256) void transpose_bf16_kernel(
    const float* __restrict__ src, u16* __restrict__ dst, int R, int C)
{
    __shared__ float t[32][33];
    const int tx = threadIdx.x & 31, ty = threadIdx.x >> 5;   // ty in 0..7
    const int c0 = blockIdx.x * 32, r0 = blockIdx.y * 32;
    #pragma unroll
    for (int i = 0; i < 4; ++i) {
        int r = ty + i * 8;
        t[r][tx] = src[(size_t)(r0 + r) * C + c0 + tx];
    }
    __syncthreads();
    #pragma unroll
    for (int i = 0; i < 4; ++i) {
        int cc = ty + i * 8;
        dst[(size_t)(c0 + cc) * R + r0 + tx] = f2bf(t[tx][cc]);
    }
}

// ---------------------------------------------------------------------------
// Persistent-B bf16 MFMA GEMM for K=512.
//   C = A(MROWS x 512) * BT^T,  BT is N x 512 bf16 (K-contiguous rows).
// Block: 64-column B-panel staged in LDS ONCE (64x512 bf16 = 64 KB, fragment-
// linear layout), ONE barrier total. 4 waves; wave = 64 rows x 64 cols.
// A-fragments stream directly global->VGPR (A row-major K-contig == A-frag
// layout); no inner barriers -> deep load pipelining via unroll.
// MODE 0: qkv epilogue -> bf16 q (x0.125) / k / v [bh][n][64]
// MODE 1: out epilogue (+bias, fp32 row-major)
// ---------------------------------------------------------------------------
template<int MODE>
__global__ __launch_bounds__(256) void gemm_bf16_mfma(
    const u16* __restrict__ A, const u16* __restrict__ BT,
    u16* __restrict__ Cq, u16* __restrict__ Ck, u16* __restrict__ Cv,
    float* __restrict__ Cout, const float* __restrict__ bias)
{
    // Bs subtile (s,n): lane l holds BT[col0+n*16+(l&15)][s*32+(l>>4)*8 + j]
    __shared__ alignas(16) u16 Bs[64 * 512];    // 64 KB

    const int tid  = threadIdx.x;
    const int wave = tid >> 6, lane = tid & 63;
    const int lm = lane & 15, lq = lane >> 4;
    const int col0 = blockIdx.x * 64;
    const int rows0 = blockIdx.y * 256;

    // ---- stage B-panel (all K) once: 64 subtiles, 16 per wave ----
    #pragma unroll
    for (int i = 0; i < 16; ++i) {
        int sub = wave * 16 + i;                // sub = s*4 + n
        int s = sub >> 2, n = sub & 3;
        gl2lds16(BT + (size_t)(col0 + n * 16 + lm) * 512 + s * 32 + lq * 8,
                 &Bs[sub * 512 + lane * 8]);
    }
    __syncthreads();                            // the only barrier

    // ---- K-loop: no barriers, A streams from global ----
    const int rbase = rows0 + wave * 64;
    const u16* aptr[4];
    #pragma unroll
    for (int ri = 0; ri < 4; ++ri) {
        int r = rbase + ri * 16 + lm;
        if (r >= MROWS) r = MROWS - 1;
        aptr[ri] = A + (size_t)r * 512 + lq * 8;
    }

    f32x4 acc[4][4];                            // [row strip][col tile]
    #pragma unroll
    for (int i = 0; i < 4; ++i)
        #pragma unroll
        for (int j = 0; j < 4; ++j) acc[i][j] = (f32x4){0.f, 0.f, 0.f, 0.f};

    #pragma unroll 4
    for (int s = 0; s < 16; ++s) {
        bf16x8 bfr[4];
        #pragma unroll
        for (int ni = 0; ni < 4; ++ni)
            bfr[ni] = *(const bf16x8*)(&Bs[(s * 4 + ni) * 512 + lane * 8]);
        #pragma unroll
        for (int ri = 0; ri < 4; ++ri) {
            bf16x8 af = *(const bf16x8*)(aptr[ri] + s * 32);
            #pragma unroll
            for (int ni = 0; ni < 4; ++ni)
                acc[ri][ni] = __builtin_amdgcn_mfma_f32_16x16x32_bf16(
                    af, bfr[ni], acc[ri][ni], 0, 0, 0);
        }
    }

    // ---- epilogue: lane l, reg r -> row = ri*16 + lq*4 + r, col = ni*16 + lm
    if (MODE == 0) {
        const int t3 = col0 >> 9;               // 0=q 1=k 2=v (uniform)
        const int h  = (col0 >> 6) & 7;         // head (uniform)
        u16* dst3 = (t3 == 0) ? Cq : (t3 == 1) ? Ck : Cv;
        const float scale = (t3 == 0) ? 0.125f : 1.0f;
        #pragma unroll
        for (int ri = 0; ri < 4; ++ri) {
            #pragma unroll
            for (int r = 0; r < 4; ++r) {
                int gr = rbase + ri * 16 + lq * 4 + r;
                if (gr >= MROWS) continue;
                int b = gr / NTOT;
                int n = gr - b * NTOT;
                size_t tok = (size_t)(b * H_ + h) * NTOT + n;
                #pragma unroll
                for (int ni = 0; ni < 4; ++ni)
                    dst3[tok * 64 + ni * 16 + lm] = f2bf(acc[ri][ni][r] * scale);
            }
        }
    } else {
        float bb[4];
        #pragma unroll
        for (int ni = 0; ni < 4; ++ni)
            bb[ni] = bias[col0 + ni * 16 + lm];
        #pragma unroll
        for (int ri = 0; ri < 4; ++ri) {
            #pragma unroll
            for (int r = 0; r < 4; ++r) {
                int gr = rbase + ri * 16 + lq * 4 + r;
                if (gr >= MROWS) continue;
                #pragma unroll
                for (int ni = 0; ni < 4; ++ni)
                    Cout[(size_t)gr * 512 + col0 + ni * 16 + lm] = acc[ri][ni][r] + bb[ni];
            }
        }
    }
}

// ---------------------------------------------------------------------------
// build per-group V^T [bh*16+f][64][KVPAD] from vbuf (incl. cls row, zero pad)
// ---------------------------------------------------------------------------
__global__ __launch_bounds__(256) void vt_build_kernel(
    const u16* __restrict__ vb, u16* __restrict__ vT)
{
    const int g = blockIdx.x;                   // bh*16 + f
    const int bh = g >> 4, f = g & 15;
    const int d = threadIdx.x & 63, jq = threadIdx.x >> 6;
    const int j0 = blockIdx.y * 32;
    u16* dst = vT + ((size_t)g * 64 + d) * KVPAD;
    #pragma unroll
    for (int i = 0; i < 8; ++i) {
        int jj = j0 + i * 4 + jq;
        u16 val = 0;
        if (jj <= 196) {
            int n = (jj == 0) ? 0 : (1 + f * NP_ + jj - 1);
            val = vb[((size_t)bh * NTOT + n) * 64 + d];
        }
        dst[jj] = val;
    }
}

// ---------------------------------------------------------------------------
// local attention, MFMA flash. One wave = one (bh, f, 16-q-row tile).
// ---------------------------------------------------------------------------
__global__ __launch_bounds__(256) void attn_mfma_kernel(
    const u16* __restrict__ qb, const u16* __restrict__ kb,
    const u16* __restrict__ vT, u16* __restrict__ attn)
{
    __shared__ alignas(16) u16 Pbuf[4 * 16 * PSTRIDE];

    const int tid  = threadIdx.x;
    const int wave = tid >> 6, lane = tid & 63;
    const int lm = lane & 15, lq = lane >> 4;
    const int task = blockIdx.x * 4 + wave;          // 0..6655
    const int mt = task % 13;
    const int gf = task / 13;
    const int f  = gf & 15;
    const int bh = gf >> 4;

    const int rq = min(mt * 16 + lm, 195);
    const u16* qrow = qb + ((size_t)bh * NTOT + (1 + f * NP_ + rq)) * 64;
    bf16x8 qf0 = *(const bf16x8*)(qrow + lq * 8);
    bf16x8 qf1 = *(const bf16x8*)(qrow + 32 + lq * 8);

    // S = Q K^T over 13 kv tiles of 16 (kv j = nt*16 + lm; j==0 is cls)
    f32x4 S[13];
    #pragma unroll
    for (int nt = 0; nt < 13; ++nt) {
        int rkc = min(nt * 16 + lm, 196);
        int nk = (rkc == 0) ? 0 : (1 + f * NP_ + rkc - 1);
        const u16* krow = kb + ((size_t)bh * NTOT + nk) * 64;
        bf16x8 kf0 = *(const bf16x8*)(krow + lq * 8);
        bf16x8 kf1 = *(const bf16x8*)(krow + 32 + lq * 8);
        f32x4 z = (f32x4){0.f, 0.f, 0.f, 0.f};
        z = __builtin_amdgcn_mfma_f32_16x16x32_bf16(qf0, kf0, z, 0, 0, 0);
        z = __builtin_amdgcn_mfma_f32_16x16x32_bf16(qf1, kf1, z, 0, 0, 0);
        S[nt] = z;
    }

    #pragma unroll
    for (int nt = 0; nt < 13; ++nt)
        if (nt * 16 + lm >= 197) {
            S[nt][0] = -INFINITY; S[nt][1] = -INFINITY;
            S[nt][2] = -INFINITY; S[nt][3] = -INFINITY;
        }

    // single-pass softmax; row = lq*4 + r, cols across the 16-lane group
    float invl[4];
    #pragma unroll
    for (int r = 0; r < 4; ++r) {
        float mx = -INFINITY;
        #pragma unroll
        for (int nt = 0; nt < 13; ++nt) mx = fmaxf(mx, S[nt][r]);
        mx = fmaxf(mx, __shfl_xor(mx, 1, 64));
        mx = fmaxf(mx, __shfl_xor(mx, 2, 64));
        mx = fmaxf(mx, __shfl_xor(mx, 4, 64));
        mx = fmaxf(mx, __shfl_xor(mx, 8, 64));
        float sum = 0.f;
        #pragma unroll
        for (int nt = 0; nt < 13; ++nt) {
            float p = __expf(S[nt][r] - mx);   // exp(-inf)=0 for masked cols
            S[nt][r] = p;
            sum += p;
        }
        sum += __shfl_xor(sum, 1, 64);
        sum += __shfl_xor(sum, 2, 64);
        sum += __shfl_xor(sum, 4, 64);
        sum += __shfl_xor(sum, 8, 64);
        invl[r] = 1.f / sum;
    }

    // P -> LDS (C-layout scatter), then re-read as A-fragments
    u16* P = Pbuf + wave * 16 * PSTRIDE;
    #pragma unroll
    for (int nt = 0; nt < 13; ++nt) {
        int col = nt * 16 + lm;
        #pragma unroll
        for (int r = 0; r < 4; ++r)
            P[(lq * 4 + r) * PSTRIDE + col] = f2bf(S[nt][r]);
    }
    {   // zero cols 208..223 (A-frag reads cover up to col 224)
        u16x4 z4 = {0, 0, 0, 0};
        *(u16x4*)(P + lm * PSTRIDE + 208 + lq * 4) = z4;
    }

    // O = P * V  (B operand from per-group V^T, kv-contiguous)
    f32x4 O[4];
    #pragma unroll
    for (int nd = 0; nd < 4; ++nd) O[nd] = (f32x4){0.f, 0.f, 0.f, 0.f};
    const u16* vbase = vT + (size_t)(bh * 16 + f) * 64 * KVPAD;
    #pragma unroll
    for (int ks = 0; ks < 7; ++ks) {
        bf16x8 pf = *(const bf16x8*)(P + lm * PSTRIDE + ks * 32 + lq * 8);
        #pragma unroll
        for (int nd = 0; nd < 4; ++nd) {
            bf16x8 vf = *(const bf16x8*)(vbase + (size_t)(nd * 16 + lm) * KVPAD + ks * 32 + lq * 8);
            O[nd] = __builtin_amdgcn_mfma_f32_16x16x32_bf16(pf, vf, O[nd], 0, 0, 0);
        }
    }

    const int b = bh >> 3, h = bh & 7;
    #pragma unroll
    for (int r = 0; r < 4; ++r) {
        int rql = mt * 16 + lq * 4 + r;
        if (rql >= 196) continue;
        int n = 1 + f * NP_ + rql;
        u16* dst = attn + ((size_t)b * NTOT + n) * 512 + h * 64;
        float s = invl[r];
        #pragma unroll
        for (int nd = 0; nd < 4; ++nd)
            dst[nd * 16 + lm] = f2bf(O[nd][r] * s);
    }
}

// ---------------------------------------------------------------------------
// cls attention, stage 1: grid (13 chunks, 32 bh), 256 threads.
// Phase A: thread = kv row; Phase B: thread = (quarter, d).
// ---------------------------------------------------------------------------
__global__ __launch_bounds__(256) void attn_cls_partial_kernel(
    const u16* __restrict__ qb, const u16* __restrict__ kb,
    const u16* __restrict__ vb, float* __restrict__ cls_m,
    float* __restrict__ cls_l, float* __restrict__ cls_o)
{
    __shared__ float qs[64];
    __shared__ float redm[4], redl[4];
    __shared__ float ps[256];
    __shared__ float so[4][64];

    const int c = blockIdx.x, bh = blockIdx.y;
    const int t = threadIdx.x;
    const int lane = t & 63, w = t >> 6;

    if (t < 64) qs[t] = bf2f(qb[(size_t)bh * NTOT * 64 + t]);   // q row 0, pre-scaled
    __syncthreads();

    // phase A: score for kv row j = c*256 + t
    const int j = c * 256 + t;
    const bool valid = (j < NTOT);
    const int jc = valid ? j : (NTOT - 1);
    const u16* krow = kb + ((size_t)bh * NTOT + jc) * 64;
    float s0 = 0.f, s1 = 0.f, s2 = 0.f, s3 = 0.f;
    #pragma unroll
    for (int i = 0; i < 8; ++i) {
        u16x8 k8 = *(const u16x8*)(krow + i * 8);
        const float* qp = qs + i * 8;
        s0 = fmaf(qp[0], bf2f(k8[0]), s0);
        s1 = fmaf(qp[1], bf2f(k8[1]), s1);
        s2 = fmaf(qp[2], bf2f(k8[2]), s2);
        s3 = fmaf(qp[3], bf2f(k8[3]), s3);
        s0 = fmaf(qp[4], bf2f(k8[4]), s0);
        s1 = fmaf(qp[5], bf2f(k8[5]), s1);
        s2 = fmaf(qp[6], bf2f(k8[6]), s2);
        s3 = fmaf(qp[7], bf2f(k8[7]), s3);
    }
    float s = (s0 + s1) + (s2 + s3);
    if (!valid) s = -INFINITY;

    // block max
    float mx = s;
    #pragma unroll
    for (int off = 1; off < 64; off <<= 1) mx = fmaxf(mx, __shfl_xor(mx, off, 64));
    if (lane == 0) redm[w] = mx;
    __syncthreads();
    mx = fmaxf(fmaxf(redm[0], redm[1]), fmaxf(redm[2], redm[3]));

    float pv = __expf(s - mx);                 // -inf -> 0
    float l = pv;
    #pragma unroll
    for (int off = 1; off < 64; off <<= 1) l += __shfl_xor(l, off, 64);
    if (lane == 0) redl[w] = l;
    ps[t] = pv;
    __syncthreads();
    l = redl[0] + redl[1] + redl[2] + redl[3];

    // phase B: o_d partial over this chunk's quarter
    const int d = lane, part = w;
    float o = 0.f;
    #pragma unroll 8
    for (int i = 0; i < 64; ++i) {
        int jj = c * 256 + part * 64 + i;
        int jjc = (jj < NTOT) ? jj : (NTOT - 1);
        o = fmaf(ps[part * 64 + i], bf2f(vb[((size_t)bh * NTOT + jjc) * 64 + d]), o);
    }
    so[part][d] = o;
    __syncthreads();
    if (t < 64) {
        float O = so[0][t] + so[1][t] + so[2][t] + so[3][t];
        int pi = bh * NCHUNK + c;
        cls_o[(size_t)pi * 64 + t] = O;
        if (t == 0) { cls_m[pi] = mx; cls_l[pi] = l; }
    }
}

// cls stage 2: merge 13 partials per bh, write bf16 row n=0.
__global__ __launch_bounds__(64) void attn_cls_merge_kernel(
    const float* __restrict__ cls_m, const float* __restrict__ cls_l,
    const float* __restrict__ cls_o, u16* __restrict__ attn)
{
    const int bh = blockIdx.x, lane = threadIdx.x;
    float M = -INFINITY;
    #pragma unroll
    for (int p = 0; p < NCHUNK; ++p) M = fmaxf(M, cls_m[bh * NCHUNK + p]);
    float L = 0.f, O = 0.f;
    #pragma unroll
    for (int p = 0; p < NCHUNK; ++p) {
        float al = __expf(cls_m[bh * NCHUNK + p] - M);
        L += cls_l[bh * NCHUNK + p] * al;
        O += cls_o[(size_t)(bh * NCHUNK + p) * 64 + lane] * al;
    }
    const int b = bh >> 3, h = bh & 7;
    attn[(size_t)b * NTOT * 512 + h * 64 + lane] = f2bf(O / L);
}

// ---------------------------------------------------------------------------
extern "C" void kernel_launch(void* const* d_in, const int* in_sizes, int n_in,
                              void* d_out, int out_size, void* d_ws, size_t ws_size,
                              hipStream_t stream) {
    const float* x    = (const float*)d_in[0];
    const float* wqkv = (const float*)d_in[1];
    const float* wout = (const float*)d_in[2];
    const float* bout = (const float*)d_in[3];

    u16* p = (u16*)d_ws;
    u16* xbf   = p;                    p += (size_t)MROWS * 512;  // reused as attn
    u16* attn  = xbf;                  // safe: xbf consumed by qkv gemm before attn writes
    u16* wqkvT = p;                    p += (size_t)1536 * 512;
    u16* woutT = p;                    p += (size_t)512 * 512;
    u16* qbuf  = p;                    p += QSZ_;
    u16* kbuf  = p;                    p += QSZ_;
    u16* vbuf  = p;                    p += QSZ_;
    u16* vT    = p;                    p += (size_t)BH_ * 16 * 64 * KVPAD;
    float* clsws = (float*)p;
    float* cls_m = clsws;                       // [32*13]
    float* cls_l = clsws + BH_ * NCHUNK;        // [32*13]
    float* cls_o = clsws + 2 * BH_ * NCHUNK;    // [32*13][64]
    float* outp  = (float*)d_out;

    // input conversions
    convert_x_kernel<<<6274, 256, 0, stream>>>(x, xbf);
    transpose_bf16_kernel<<<dim3(48, 16), 256, 0, stream>>>(wqkv, wqkvT, 512, 1536);
    transpose_bf16_kernel<<<dim3(16, 16), 256, 0, stream>>>(wout, woutT, 512, 512);
    // qkv = x @ W_qkv  (persistent-B, barrier-free K-loop) -> bf16 q/k/v
    gemm_bf16_mfma<0><<<dim3(24, 50), 256, 0, stream>>>(
        xbf, wqkvT, qbuf, kbuf, vbuf, nullptr, nullptr);
    // per-group V^T (incl. cls row + zero pad)
    vt_build_kernel<<<dim3(512, 7), 256, 0, stream>>>(vbuf, vT);
    // attention
    attn_mfma_kernel<<<1664, 256, 0, stream>>>(qbuf, kbuf, vT, attn);
    attn_cls_partial_kernel<<<dim3(NCHUNK, 32), 256, 0, stream>>>(
        qbuf, kbuf, vbuf, cls_m, cls_l, cls_o);
    attn_cls_merge_kernel<<<32, 64, 0, stream>>>(cls_m, cls_l, cls_o, attn);
    // out = attn @ W_out + b_out  (persistent-B, barrier-free K-loop)
    gemm_bf16_mfma<1><<<dim3(8, 50), 256, 0, stream>>>(
        attn, woutT, nullptr, nullptr, nullptr, outp, bout);
}